// Round 1
// 227.512 us; speedup vs baseline: 1.0584x; 1.0584x over previous
//
#include <hip/hip_runtime.h>
#include <hip/hip_bf16.h>

// GCN forward, MI355X. Round 10: atomic-free CSR fill.
//   memset(deg|desc|pooled|cnt)   [one region]
//   cvt_we    : W->bf16 canonical (W1..W4 fragment-major) | batch->i32 |
//               degree count from raw edges, CAPTURING the atomicAdd return
//               as the edge's rank within its dst row (coalesced rank[e])
//   scan      : ONE dispatch, decoupled-lookback (64-bit packed state|value
//               atomics, fence-free; 196 blocks all co-resident)
//   fill_gemm1: block-range split — ATOMIC-FREE packed uint2 CSR fill
//               (pos = row_ptr[dst] + rank[e]) | X@W1 MFMA
//   aggemm x3 : gather+bias+relu at the AGG's grid (16-32 nodes/block,
//               max occupancy) -> 4KB LDS tile -> MFMA next layer in-block
//   agg_pool  : last-layer gather (LPG=8) + LDS graph pool -> atomics
//   final     : 64x16 @ 16x10 linear, dtype-dispatched store
//
// Lessons: R5 — fusing at the GEMM's grid (N/128) craters occupancy to 13%;
// fuse at the AGG's grid instead. R7 — no per-block __threadfence in wide
// grids (L2 writeback storm); lookback uses single-location packed atomics.
// R10 — fill_gemm1 was atomic-throughput-bound (~5 atomics/cycle chip-wide,
// MfmaUtil 1.2%, VALUBusy 3.9%, 18% HBM): the cursor atomics duplicated the
// degree-count atomics already paid in cvt_we; capturing that return value
// as rank[e] makes the fill a pure gather+scatter.
//
// MFMA 16x16x32_bf16 layouts (verified): A[m=l&15][k=(l>>4)*8+j] (k-contig);
// B frag f at Wf[f*1024 + l*16..+16] = B[kb*32+(l>>4)*8+j][ct*16+(l&15)],
// f=ct*KB+kb; C/D col=l&15, row=(l>>4)*4+reg.

#define N_GRAPHS 64
#define N_CLASSES 10

typedef short bf8_t __attribute__((ext_vector_type(8)));
typedef float f4_t  __attribute__((ext_vector_type(4)));

__device__ __forceinline__ float b2f(unsigned int u) {
  return __uint_as_float(u << 16);
}
__device__ __forceinline__ unsigned short f2b(float f) {
  unsigned int x = __float_as_uint(f);
  x += 0x7fffu + ((x >> 16) & 1u);   // RNE (finite values only)
  return (unsigned short)(x >> 16);
}

// Per-block dtype detect; call with all 256 threads pre-divergence.
__device__ __forceinline__ void block_detect(const unsigned int* __restrict__ xraw,
    const unsigned int* __restrict__ eraw, int* f32, int* i64) {
  __shared__ int c_bf, c_nz;
  if (threadIdx.x == 0) { c_bf = 0; c_nz = 0; }
  __syncthreads();
  unsigned int d = xraw[threadIdx.x & 255];
  int e = (int)(((d & 0xffffu) >> 7) & 0xff);
  if (e >= 100 && e <= 140) atomicAdd(&c_bf, 1);
  if (eraw && threadIdx.x < 64 && eraw[2 * threadIdx.x + 1] != 0u) atomicAdd(&c_nz, 1);
  __syncthreads();
  *f32 = (c_bf < 150) ? 1 : 0;
  if (i64) *i64 = (c_nz == 0) ? 1 : 0;
}

struct WPtrs { const void* p[10]; };
static constexpr int WSEG[10] = {16384, 128, 8192, 64, 2048, 32, 512, 16, 160, 10};
static constexpr int WTOTAL   = 27546;
static constexpr int WOFF[10] = {0, 16384, 16512, 24704, 24768, 26816, 26848, 27360, 27376, 27536};

// blocks [0,BW): weights; [BW,BW+BB): batch; rest: degree count from eraw,
// capturing the per-edge rank (old degree value) to rank[e].
__global__ __launch_bounds__(256) void cvt_we_kernel(
    const unsigned int* __restrict__ xraw, WPtrs wp, unsigned short* __restrict__ wc,
    const int* __restrict__ braw, int* __restrict__ b32,
    const int* __restrict__ eraw, int* __restrict__ deg, int* __restrict__ rank,
    int BW, int BB, int n, int E) {
  int f32, i64;
  block_detect(xraw, (const unsigned int*)eraw, &f32, &i64);
  const int bid = blockIdx.x;
  if (bid < BW) {
    int i = bid * 256 + threadIdx.x;
    if (i >= WTOTAL) return;
    int off = i, s = 0;
    #pragma unroll
    for (int t = 0; t < 10; ++t) {
      if (s == 0 && off >= WSEG[t]) { off -= WSEG[t]; } else if (s == 0) { s = t + 1; }
    }
    s -= 1;
    int soff = off;
    if ((s & 1) == 0 && s <= 6) {           // W1..W4 -> fragment-major
      int KB, FOUT;
      if (s == 0)      { KB = 4; FOUT = 128; }
      else if (s == 2) { KB = 4; FOUT = 64; }
      else if (s == 4) { KB = 2; FOUT = 32; }
      else             { KB = 1; FOUT = 16; }
      int j = off & 7, l = (off >> 3) & 63, f = off >> 9;
      int ct = f / KB, kb = f - ct * KB;
      int k = kb * 32 + ((l >> 4) << 3) + j;
      int nn = ct * 16 + (l & 15);
      soff = k * FOUT + nn;
    }
    const void* p = wp.p[s];
    wc[WOFF[s] + off] = f32 ? f2b(((const float*)p)[soff])
                            : ((const unsigned short*)p)[soff];
  } else if (bid < BW + BB) {
    int i = (bid - BW) * 256 + threadIdx.x;
    if (i < n) b32[i] = i64 ? braw[2 * i] : braw[i];
  } else {
    int e = (bid - BW - BB) * 256 + threadIdx.x;
    if (e >= E) return;
    int d = i64 ? eraw[2 * (E + e)] : eraw[E + e];
    rank[e] = atomicAdd(&deg[d], 1);
  }
}

// Single-dispatch scan: per-block local scan + decoupled lookback via packed
// (state<<62 | value) 64-bit atomics. state: 1=aggregate, 2=inclusive prefix.
// No fences — value travels inside the same atomic location.
__global__ __launch_bounds__(256) void scan_kernel(const int* __restrict__ deg,
    int* __restrict__ row_ptr, float* __restrict__ dinv,
    unsigned long long* __restrict__ desc, int n) {
  __shared__ int ws[4];
  __shared__ int s_total;
  __shared__ unsigned int s_prev;
  const int b = blockIdx.x, tid = threadIdx.x, lane = tid & 63, wv = tid >> 6;
  const int i = b * 256 + tid;
  int v = (i < n) ? deg[i] : 0;
  int x = v;
  #pragma unroll
  for (int off = 1; off < 64; off <<= 1) {
    int y = __shfl_up(x, off, 64);
    if (lane >= off) x += y;
  }
  if (lane == 63) ws[wv] = x;
  __syncthreads();
  int wbase = 0;
  for (int w = 0; w < wv; ++w) wbase += ws[w];
  int incl = x + wbase;
  if (tid == 0) {
    int tot = ws[0] + ws[1] + ws[2] + ws[3];
    s_total = tot;
    unsigned long long st = (b == 0) ? (2ULL << 62) : (1ULL << 62);
    atomicExch(&desc[b], st | (unsigned long long)(unsigned int)tot);
    if (b == 0) s_prev = 0u;
  }
  __syncthreads();
  if (b > 0 && wv == 0) {
    unsigned int running = 0;
    int j = b - 1;
    while (true) {
      int idx = j - lane;
      unsigned long long d;
      if (idx >= 0) {
        do { d = atomicAdd(&desc[idx], 0ULL); } while ((d >> 62) == 0ULL);
      } else {
        d = (2ULL << 62);
      }
      unsigned long long ball = __ballot((d >> 62) == 2ULL);
      int fp = ball ? (__ffsll((unsigned long long)ball) - 1) : 64;
      unsigned int contrib = (lane <= fp) ? (unsigned int)(d & 0xffffffffULL) : 0u;
      #pragma unroll
      for (int o = 32; o; o >>= 1) contrib += __shfl_xor(contrib, o, 64);
      running += contrib;
      if (fp < 64) break;
      j -= 64;
    }
    if (lane == 0) {
      atomicExch(&desc[b], (2ULL << 62) |
                 (unsigned long long)(unsigned int)(running + (unsigned int)s_total));
      s_prev = running;
    }
  }
  __syncthreads();
  int tot = (int)s_prev + incl;
  if (i < n) {
    row_ptr[i + 1] = tot;
    dinv[i] = rsqrtf((float)v + 1.0f);
  }
  if (i == 0) row_ptr[0] = 0;
}

// Merged: blocks [0,BE) fill packed CSR from raw edges (atomic-free:
// pos = row_ptr[dst] + rank[e]); rest X@W1 via MFMA.
__global__ __launch_bounds__(256) void fill_gemm1_kernel(
    const int* __restrict__ eraw, const unsigned int* __restrict__ xraw,
    const int* __restrict__ row_ptr, const int* __restrict__ rank,
    const float* __restrict__ dinv, uint2* __restrict__ csr,
    const unsigned short* __restrict__ Wf, unsigned short* __restrict__ H,
    int BE, int n, int E) {
  int f32, i64;
  block_detect(xraw, (const unsigned int*)eraw, &f32, &i64);
  if (blockIdx.x < BE) {
    int e = blockIdx.x * 256 + threadIdx.x;
    if (e < E) {
      int s, d;
      if (i64) { s = eraw[2 * e]; d = eraw[2 * (E + e)]; }
      else     { s = eraw[e];     d = eraw[E + e]; }
      int pos = row_ptr[d] + rank[e];
      uint2 v;
      v.x = (unsigned int)s;
      v.y = __float_as_uint(dinv[s] * dinv[d]);
      csr[pos] = v;
    }
    return;
  }
  const int b2 = blockIdx.x - BE;
  const int l = threadIdx.x & 63;
  const int r16 = l & 15, quad = l >> 4;
  const int m0 = (b2 * 4 + (threadIdx.x >> 6)) * 32;
  if (m0 >= n) return;
  bf8_t afrag[2][4];
  #pragma unroll
  for (int mt = 0; mt < 2; ++mt) {
    int node = m0 + mt * 16 + r16;
    int nc = node < n ? node : n - 1;
    if (f32) {
      const float* xp = (const float*)xraw + (size_t)nc * 128 + quad * 8;
      #pragma unroll
      for (int kb = 0; kb < 4; ++kb) {
        const float4* p4 = (const float4*)(xp + kb * 32);
        float4 u0 = p4[0], u1 = p4[1];
        bf8_t a;
        a[0] = (short)f2b(u0.x); a[1] = (short)f2b(u0.y);
        a[2] = (short)f2b(u0.z); a[3] = (short)f2b(u0.w);
        a[4] = (short)f2b(u1.x); a[5] = (short)f2b(u1.y);
        a[6] = (short)f2b(u1.z); a[7] = (short)f2b(u1.w);
        afrag[mt][kb] = a;
      }
    } else {
      const unsigned short* xp = (const unsigned short*)xraw + (size_t)nc * 128 + quad * 8;
      #pragma unroll
      for (int kb = 0; kb < 4; ++kb)
        afrag[mt][kb] = *(const bf8_t*)(xp + kb * 32);
    }
  }
  #pragma unroll
  for (int ct = 0; ct < 8; ++ct) {
    bf8_t bfrag[4];
    #pragma unroll
    for (int kb = 0; kb < 4; ++kb)
      bfrag[kb] = *(const bf8_t*)(Wf + ((ct * 4 + kb) * 64 + l) * 8);
    #pragma unroll
    for (int mt = 0; mt < 2; ++mt) {
      f4_t acc = {0.f, 0.f, 0.f, 0.f};
      #pragma unroll
      for (int kb = 0; kb < 4; ++kb)
        acc = __builtin_amdgcn_mfma_f32_16x16x32_bf16(afrag[mt][kb], bfrag[kb], acc, 0, 0, 0);
      #pragma unroll
      for (int r = 0; r < 4; ++r) {
        int node = m0 + mt * 16 + quad * 4 + r;
        if (node < n)
          H[(size_t)node * 128 + ct * 16 + r16] = f2b(acc[r]);
      }
    }
  }
}

// ---- generic per-lane vector of DW dwords ----
template<int DW> struct UVec { unsigned int d[DW]; };
template<int DW>
__device__ __forceinline__ UVec<DW> uload(const unsigned int* p) {
  UVec<DW> r;
  if constexpr (DW == 4) { uint4 v = *(const uint4*)p; r.d[0]=v.x; r.d[1]=v.y; r.d[2]=v.z; r.d[3]=v.w; }
  else if constexpr (DW == 2) { uint2 v = *(const uint2*)p; r.d[0]=v.x; r.d[1]=v.y; }
  else { r.d[0] = *p; }
  return r;
}
template<int DW>
__device__ __forceinline__ void ustore(unsigned int* p, const UVec<DW>& v) {
  if constexpr (DW == 4) { *(uint4*)p = make_uint4(v.d[0], v.d[1], v.d[2], v.d[3]); }
  else if constexpr (DW == 2) { *(uint2*)p = make_uint2(v.d[0], v.d[1]); }
  else { *p = v.d[0]; }
}

// Fused agg(FIN, bias, relu) -> LDS tile -> MFMA @ Wf(FIN x FOUT) -> Hout.
// Grid = agg's grid (NPB=256/LPG nodes per block) so occupancy is preserved
// (R5 lesson). Gemm rows only need their own node's agg output.
template<int FIN, int FOUT, int LPG>
__global__ __launch_bounds__(256) void aggemm_kernel(
    const unsigned short* __restrict__ Hin,
    const int* __restrict__ row_ptr, const uint2* __restrict__ csr,
    const float* __restrict__ dinv, const unsigned short* __restrict__ bias,
    const unsigned short* __restrict__ Wf, unsigned short* __restrict__ Hout, int n) {
  constexpr int DW  = FIN / LPG / 2;     // dwords per lane
  constexpr int NPB = 256 / LPG;         // nodes per block (16 or 32)
  constexpr int LD  = FIN + 8;           // LDS row pitch in shorts
  constexpr int KB  = FIN / 32;
  constexpr int CT  = FOUT / 16;
  constexpr int MT  = NPB / 16;
  __shared__ unsigned short T[NPB * LD];
  const int r = threadIdx.x / LPG, l = threadIdx.x % LPG;
  const int node0 = blockIdx.x * NPB;
  const int g = node0 + r;
  const unsigned int* H2 = (const unsigned int*)Hin;
  UVec<DW> o;
  #pragma unroll
  for (int d = 0; d < DW; ++d) o.d[d] = 0u;
  if (g < n) {
    float di = dinv[g];
    float c0 = di * di;
    float a[2 * DW];
    UVec<DW> hv = uload<DW>(H2 + (size_t)g * (FIN / 2) + l * DW);
    #pragma unroll
    for (int d = 0; d < DW; ++d) {
      a[2*d]   = b2f(hv.d[d] & 0xffffu) * c0;
      a[2*d+1] = b2f(hv.d[d] >> 16) * c0;
    }
    const int e0 = row_ptr[g], e1 = row_ptr[g + 1];
    for (int base = e0; base < e1; base += LPG) {
      int cnt = e1 - base < LPG ? e1 - base : LPG;
      uint2 my = csr[(base + l < e1) ? (base + l) : (e1 - 1)];
      for (int j = 0; j < cnt; ++j) {
        int s = __shfl((int)my.x, j, LPG);
        float c = __uint_as_float(__shfl((int)my.y, j, LPG));
        UVec<DW> v = uload<DW>(H2 + (size_t)s * (FIN / 2) + l * DW);
        #pragma unroll
        for (int d = 0; d < DW; ++d) {
          a[2*d]   = fmaf(b2f(v.d[d] & 0xffffu), c, a[2*d]);
          a[2*d+1] = fmaf(b2f(v.d[d] >> 16), c, a[2*d+1]);
        }
      }
    }
    UVec<DW> bb = uload<DW>((const unsigned int*)bias + l * DW);
    #pragma unroll
    for (int d = 0; d < DW; ++d) {
      float lo = fmaxf(a[2*d]   + b2f(bb.d[d] & 0xffffu), 0.f);
      float hi = fmaxf(a[2*d+1] + b2f(bb.d[d] >> 16), 0.f);
      o.d[d] = (unsigned int)f2b(lo) | ((unsigned int)f2b(hi) << 16);
    }
  }
  ustore<DW>((unsigned int*)&T[r * LD + l * DW * 2], o);
  __syncthreads();
  // ---- MFMA phase: wave w covers (mt, ct) combo ----
  const int w = threadIdx.x >> 6;
  if (w < MT * CT && node0 < n) {
    const int mt = w / CT, ct = w % CT;
    const int ll = threadIdx.x & 63;
    const int r16 = ll & 15, quad = ll >> 4;
    bf8_t afrag[KB], bfrag[KB];
    #pragma unroll
    for (int kb = 0; kb < KB; ++kb) {
      afrag[kb] = *(const bf8_t*)(&T[(mt * 16 + r16) * LD + quad * 8 + kb * 32]);
      bfrag[kb] = *(const bf8_t*)(Wf + ((ct * KB + kb) * 64 + ll) * 8);
    }
    f4_t acc = {0.f, 0.f, 0.f, 0.f};
    #pragma unroll
    for (int kb = 0; kb < KB; ++kb)
      acc = __builtin_amdgcn_mfma_f32_16x16x32_bf16(afrag[kb], bfrag[kb], acc, 0, 0, 0);
    #pragma unroll
    for (int rr = 0; rr < 4; ++rr) {
      int node = node0 + mt * 16 + quad * 4 + rr;
      if (node < n)
        Hout[(size_t)node * FOUT + ct * 16 + r16] = f2b(acc[rr]);
    }
  }
}

// Fused last-layer agg + mean-pool. LPG=8, 32 nodes/block.
__global__ __launch_bounds__(256) void agg_pool_kernel(
    const unsigned short* __restrict__ Hin,
    const int* __restrict__ row_ptr, const uint2* __restrict__ csr,
    const float* __restrict__ dinv, const unsigned short* __restrict__ bias,
    const int* __restrict__ batch, float* __restrict__ pooled,
    float* __restrict__ cnt, int n) {
  __shared__ float acc[N_GRAPHS * 16];
  __shared__ float ccnt[N_GRAPHS];
  for (int i = threadIdx.x; i < N_GRAPHS * 16; i += 256) acc[i] = 0.f;
  if (threadIdx.x < N_GRAPHS) ccnt[threadIdx.x] = 0.f;
  __syncthreads();
  const int r = threadIdx.x >> 3, l = threadIdx.x & 7;
  const int g = blockIdx.x * 32 + r;
  if (g < n) {
    const unsigned int* H2 = (const unsigned int*)Hin;
    float di = dinv[g];
    float c0 = di * di;
    unsigned int hv = H2[(size_t)g * 8 + l];
    float a0 = b2f(hv & 0xffffu) * c0;
    float a1 = b2f(hv >> 16) * c0;
    const int e0 = row_ptr[g], e1 = row_ptr[g + 1];
    for (int base = e0; base < e1; base += 8) {
      int cnt2 = e1 - base < 8 ? e1 - base : 8;
      uint2 my = csr[(base + l < e1) ? (base + l) : (e1 - 1)];
      for (int j = 0; j < cnt2; ++j) {
        int s = __shfl((int)my.x, j, 8);
        float c = __uint_as_float(__shfl((int)my.y, j, 8));
        unsigned int v = H2[(size_t)s * 8 + l];
        a0 = fmaf(b2f(v & 0xffffu), c, a0);
        a1 = fmaf(b2f(v >> 16), c, a1);
      }
    }
    unsigned int bb = ((const unsigned int*)bias)[l];
    a0 = fmaxf(a0 + b2f(bb & 0xffffu), 0.f);
    a1 = fmaxf(a1 + b2f(bb >> 16), 0.f);
    int gb = batch[g];
    atomicAdd(&acc[gb * 16 + l * 2 + 0], a0);
    atomicAdd(&acc[gb * 16 + l * 2 + 1], a1);
    if (l == 0) atomicAdd(&ccnt[gb], 1.f);
  }
  __syncthreads();
  for (int i = threadIdx.x; i < N_GRAPHS * 16; i += 256)
    if (acc[i] != 0.f) atomicAdd(&pooled[i], acc[i]);
  if (threadIdx.x < N_GRAPHS && ccnt[threadIdx.x] != 0.f)
    atomicAdd(&cnt[threadIdx.x], ccnt[threadIdx.x]);
}

__global__ __launch_bounds__(256) void final_kernel(const float* __restrict__ pooled,
    const float* __restrict__ cnt, const unsigned short* __restrict__ wc,
    void* __restrict__ out, const unsigned int* __restrict__ xraw) {
  int f32;
  block_detect(xraw, nullptr, &f32, nullptr);
  int id = blockIdx.x * 256 + threadIdx.x;
  if (id >= N_GRAPHS * N_CLASSES) return;
  const unsigned short* Wlin = wc + WOFF[8];
  const unsigned short* blin = wc + WOFF[9];
  int g = id / N_CLASSES, c = id - g * N_CLASSES;
  float inv = 1.0f / fmaxf(cnt[g], 1.0f);
  float a = b2f(blin[c]);
  #pragma unroll
  for (int f = 0; f < 16; ++f)
    a = fmaf(pooled[g * 16 + f] * inv, b2f(Wlin[f * N_CLASSES + c]), a);
  if (f32) ((float*)out)[id] = a;
  else     ((unsigned short*)out)[id] = f2b(a);
}

extern "C" void kernel_launch(void* const* d_in, const int* in_sizes, int n_in,
                              void* d_out, int out_size, void* d_ws, size_t ws_size,
                              hipStream_t stream) {
  const unsigned int* xraw = (const unsigned int*)d_in[0];
  const int* eraw          = (const int*)d_in[1];
  const int* braw          = (const int*)d_in[2];

  const int N = in_sizes[2];
  const int E = in_sizes[1] / 2;
  const int nb = (N + 255) / 256;

  char* p = (char*)d_ws;
  auto alloc = [&](size_t bytes) -> void* {
    void* r = (void*)p;
    p += (bytes + 255) & ~(size_t)255;
    return r;
  };
  // zero region: deg | desc | pooled | cnt  (single memset)
  const size_t off_desc = ((size_t)N * 4 + 255) & ~(size_t)255;
  const size_t off_pool = (off_desc + (size_t)nb * 8 + 255) & ~(size_t)255;
  const size_t ztotal   = off_pool + (N_GRAPHS * 16 + N_GRAPHS) * 4;
  char* zbase = (char*)alloc(ztotal);
  int*   deg    = (int*)zbase;
  unsigned long long* desc = (unsigned long long*)(zbase + off_desc);
  float* pooled = (float*)(zbase + off_pool);
  float* cntf   = pooled + N_GRAPHS * 16;

  int*   row_ptr  = (int*)  alloc((size_t)(N + 1) * 4);
  int*   rank     = (int*)  alloc((size_t)E * 4);
  float* dinv     = (float*)alloc((size_t)N * 4);
  int*   batch32  = (int*)  alloc((size_t)N * 4);
  uint2* csr      = (uint2*)alloc((size_t)E * 8);
  unsigned short* wcan  = (unsigned short*)alloc((size_t)WTOTAL * 2);
  unsigned short* hbufA = (unsigned short*)alloc((size_t)N * 128 * 2);
  unsigned short* hbufB = (unsigned short*)alloc((size_t)N * 128 * 2);

  hipMemsetAsync(zbase, 0, ztotal, stream);

  WPtrs wp;
  for (int i = 0; i < 10; ++i) wp.p[i] = d_in[3 + i];

  const int BW = (WTOTAL + 255) / 256;
  const int BB = nb;
  const int BE = (E + 255) / 256;
  cvt_we_kernel<<<BW + BB + BE, 256, 0, stream>>>(xraw, wp, wcan, braw, batch32,
      eraw, deg, rank, BW, BB, N, E);

  scan_kernel<<<nb, 256, 0, stream>>>(deg, row_ptr, dinv, desc, N);

  const unsigned short* W1 = wcan + WOFF[0];
  const unsigned short* b1 = wcan + WOFF[1];
  const unsigned short* W2 = wcan + WOFF[2];
  const unsigned short* b2 = wcan + WOFF[3];
  const unsigned short* W3 = wcan + WOFF[4];
  const unsigned short* b3 = wcan + WOFF[5];
  const unsigned short* W4 = wcan + WOFF[6];
  const unsigned short* b4 = wcan + WOFF[7];

  const int G1 = (N + 127) / 128;
  fill_gemm1_kernel<<<BE + G1, 256, 0, stream>>>(eraw, xraw, row_ptr, rank, dinv,
      csr, W1, hbufA, BE, N, E);

  aggemm_kernel<128, 64, 16><<<(N + 15) / 16, 256, 0, stream>>>(
      hbufA, row_ptr, csr, dinv, b1, W2, hbufB, N);
  aggemm_kernel<64, 32, 8><<<(N + 31) / 32, 256, 0, stream>>>(
      hbufB, row_ptr, csr, dinv, b2, W3, hbufA, N);
  aggemm_kernel<32, 16, 8><<<(N + 31) / 32, 256, 0, stream>>>(
      hbufA, row_ptr, csr, dinv, b3, W4, hbufB, N);
  agg_pool_kernel<<<(N + 31) / 32, 256, 0, stream>>>(hbufB, row_ptr, csr, dinv, b4,
      batch32, pooled, cntf, N);

  final_kernel<<<(N_GRAPHS * N_CLASSES + 255) / 256, 256, 0, stream>>>(pooled, cntf, wcan, d_out, xraw);
}

// Round 2
// 226.839 us; speedup vs baseline: 1.0616x; 1.0030x over previous
//
#include <hip/hip_runtime.h>
#include <hip/hip_bf16.h>

// GCN forward, MI355X. Round 11: padded atomics + GEMM1 overlapped with them.
//   memset(deg|desc|pooled|cnt)   [one region]
//   cvtwe_gemm1: ONE dispatch, block ranges ordered for overlap:
//                [0,G1)   X@W1 MFMA (W1 self-staged raw->canonical in LDS)
//                [..+BW)  W->bf16 canonical (W2..W4 fragment-major)
//                [..+BB)  batch->i32
//                [rest)   degree count, atomicAdd on LINE-PADDED deg
//                         (stride 16 ints = 1 counter/64B line; ~12 same-line
//                         collisions instead of ~192), return value -> rank[e]
//   scan       : decoupled-lookback (64-bit packed state|value atomics)
//   fill       : pure atomic-free scatter  pos = row_ptr[dst] + rank[e]
//   aggemm x3  : gather+bias+relu at the AGG's grid -> LDS tile -> MFMA
//   agg_pool   : last-layer gather (LPG=8) + LDS graph pool -> atomics
//   final      : 64x16 @ 16x10 linear, dtype-dispatched store
//
// Lessons: R5 — fusing at the GEMM's grid craters occupancy; fuse at the
// AGG's grid. R7 — no per-block __threadfence in wide grids. R10 — cursor
// atomics duplicated degree atomics; capture the degree atomicAdd return as
// rank[e]. R11 — dense deg = 16 counters/line => ~192 same-line RMWs
// serialize at the cache atomic unit; pad to line-per-counter. GEMM blocks
// lead the merged grid so MFMA work hides under the atomic phase's latency.
//
// MFMA 16x16x32_bf16 layouts (verified): A[m=l&15][k=(l>>4)*8+j] (k-contig);
// B frag f at Wf[f*512 + l*8..+8] = B[kb*32+(l>>4)*8+j][ct*16+(l&15)],
// f=ct*KB+kb; C/D col=l&15, row=(l>>4)*4+reg.

#define N_GRAPHS 64
#define N_CLASSES 10

typedef short bf8_t __attribute__((ext_vector_type(8)));
typedef float f4_t  __attribute__((ext_vector_type(4)));

__device__ __forceinline__ float b2f(unsigned int u) {
  return __uint_as_float(u << 16);
}
__device__ __forceinline__ unsigned short f2b(float f) {
  unsigned int x = __float_as_uint(f);
  x += 0x7fffu + ((x >> 16) & 1u);   // RNE (finite values only)
  return (unsigned short)(x >> 16);
}

// Per-block dtype detect; call with all 256 threads pre-divergence.
__device__ __forceinline__ void block_detect(const unsigned int* __restrict__ xraw,
    const unsigned int* __restrict__ eraw, int* f32, int* i64) {
  __shared__ int c_bf, c_nz;
  if (threadIdx.x == 0) { c_bf = 0; c_nz = 0; }
  __syncthreads();
  unsigned int d = xraw[threadIdx.x & 255];
  int e = (int)(((d & 0xffffu) >> 7) & 0xff);
  if (e >= 100 && e <= 140) atomicAdd(&c_bf, 1);
  if (eraw && threadIdx.x < 64 && eraw[2 * threadIdx.x + 1] != 0u) atomicAdd(&c_nz, 1);
  __syncthreads();
  *f32 = (c_bf < 150) ? 1 : 0;
  if (i64) *i64 = (c_nz == 0) ? 1 : 0;
}

struct WPtrs { const void* p[10]; };
static constexpr int WSEG[10] = {16384, 128, 8192, 64, 2048, 32, 512, 16, 160, 10};
static constexpr int WTOTAL   = 27546;
static constexpr int WOFF[10] = {0, 16384, 16512, 24704, 24768, 26816, 26848, 27360, 27376, 27536};

// Merged: [0,G1) gemm1 | [G1,G1+BW) weights | [..+BB) batch | rest edge atomics.
__global__ __launch_bounds__(256) void cvtwe_gemm1_kernel(
    const unsigned int* __restrict__ xraw, WPtrs wp, unsigned short* __restrict__ wc,
    const int* __restrict__ braw, int* __restrict__ b32,
    const int* __restrict__ eraw, int* __restrict__ deg, int* __restrict__ rank,
    unsigned short* __restrict__ H,
    int G1, int BW, int BB, int n, int E) {
  __shared__ unsigned short Wlds[16384];   // 32KB: W1 canonical fragments
  int f32, i64;
  block_detect(xraw, (const unsigned int*)eraw, &f32, &i64);
  const int bid = blockIdx.x;
  if (bid < G1) {
    // ---- stage raw W1 (f32 or bf16, [k][n] row-major) -> canonical LDS ----
    const void* w1 = wp.p[0];
    #pragma unroll 4
    for (int it = 0; it < 64; ++it) {
      int srcI = it * 256 + threadIdx.x;
      int k = srcI >> 7, nn = srcI & 127;
      int kb = k >> 5, j = k & 7, quad = (k >> 3) & 3;
      int ct = nn >> 4, r16c = nn & 15;
      int l = quad * 16 + r16c;
      int f = ct * 4 + kb;
      unsigned short w = f32 ? f2b(((const float*)w1)[srcI])
                             : ((const unsigned short*)w1)[srcI];
      Wlds[(f * 64 + l) * 8 + j] = w;
    }
    __syncthreads();
    const int l = threadIdx.x & 63;
    const int r16 = l & 15, quad = l >> 4;
    const int m0 = (bid * 4 + (threadIdx.x >> 6)) * 32;
    if (m0 >= n) return;
    bf8_t afrag[2][4];
    #pragma unroll
    for (int mt = 0; mt < 2; ++mt) {
      int node = m0 + mt * 16 + r16;
      int nc = node < n ? node : n - 1;
      if (f32) {
        const float* xp = (const float*)xraw + (size_t)nc * 128 + quad * 8;
        #pragma unroll
        for (int kb = 0; kb < 4; ++kb) {
          const float4* p4 = (const float4*)(xp + kb * 32);
          float4 u0 = p4[0], u1 = p4[1];
          bf8_t a;
          a[0] = (short)f2b(u0.x); a[1] = (short)f2b(u0.y);
          a[2] = (short)f2b(u0.z); a[3] = (short)f2b(u0.w);
          a[4] = (short)f2b(u1.x); a[5] = (short)f2b(u1.y);
          a[6] = (short)f2b(u1.z); a[7] = (short)f2b(u1.w);
          afrag[mt][kb] = a;
        }
      } else {
        const unsigned short* xp = (const unsigned short*)xraw + (size_t)nc * 128 + quad * 8;
        #pragma unroll
        for (int kb = 0; kb < 4; ++kb)
          afrag[mt][kb] = *(const bf8_t*)(xp + kb * 32);
      }
    }
    #pragma unroll
    for (int ct = 0; ct < 8; ++ct) {
      bf8_t bfrag[4];
      #pragma unroll
      for (int kb = 0; kb < 4; ++kb)
        bfrag[kb] = *(const bf8_t*)(&Wlds[((ct * 4 + kb) * 64 + l) * 8]);
      #pragma unroll
      for (int mt = 0; mt < 2; ++mt) {
        f4_t acc = {0.f, 0.f, 0.f, 0.f};
        #pragma unroll
        for (int kb = 0; kb < 4; ++kb)
          acc = __builtin_amdgcn_mfma_f32_16x16x32_bf16(afrag[mt][kb], bfrag[kb], acc, 0, 0, 0);
        #pragma unroll
        for (int r = 0; r < 4; ++r) {
          int node = m0 + mt * 16 + quad * 4 + r;
          if (node < n)
            H[(size_t)node * 128 + ct * 16 + r16] = f2b(acc[r]);
        }
      }
    }
  } else if (bid < G1 + BW) {
    int i = (bid - G1) * 256 + threadIdx.x;
    if (i >= WTOTAL) return;
    int off = i, s = 0;
    #pragma unroll
    for (int t = 0; t < 10; ++t) {
      if (s == 0 && off >= WSEG[t]) { off -= WSEG[t]; } else if (s == 0) { s = t + 1; }
    }
    s -= 1;
    int soff = off;
    if ((s & 1) == 0 && s <= 6) {           // W1..W4 -> fragment-major
      int KB, FOUT;
      if (s == 0)      { KB = 4; FOUT = 128; }
      else if (s == 2) { KB = 4; FOUT = 64; }
      else if (s == 4) { KB = 2; FOUT = 32; }
      else             { KB = 1; FOUT = 16; }
      int j = off & 7, l = (off >> 3) & 63, f = off >> 9;
      int ct = f / KB, kb = f - ct * KB;
      int k = kb * 32 + ((l >> 4) << 3) + j;
      int nn = ct * 16 + (l & 15);
      soff = k * FOUT + nn;
    }
    const void* p = wp.p[s];
    wc[WOFF[s] + off] = f32 ? f2b(((const float*)p)[soff])
                            : ((const unsigned short*)p)[soff];
  } else if (bid < G1 + BW + BB) {
    int i = (bid - G1 - BW) * 256 + threadIdx.x;
    if (i < n) b32[i] = i64 ? braw[2 * i] : braw[i];
  } else {
    int e = (bid - G1 - BW - BB) * 256 + threadIdx.x;
    if (e >= E) return;
    int d = i64 ? eraw[2 * (E + e)] : eraw[E + e];
    rank[e] = atomicAdd(&deg[(size_t)d << 4], 1);   // line-padded counter
  }
}

// Single-dispatch scan: per-block local scan + decoupled lookback via packed
// (state<<62 | value) 64-bit atomics. state: 1=aggregate, 2=inclusive prefix.
__global__ __launch_bounds__(256) void scan_kernel(const int* __restrict__ deg,
    int* __restrict__ row_ptr, float* __restrict__ dinv,
    unsigned long long* __restrict__ desc, int n) {
  __shared__ int ws[4];
  __shared__ int s_total;
  __shared__ unsigned int s_prev;
  const int b = blockIdx.x, tid = threadIdx.x, lane = tid & 63, wv = tid >> 6;
  const int i = b * 256 + tid;
  int v = (i < n) ? deg[(size_t)i << 4] : 0;
  int x = v;
  #pragma unroll
  for (int off = 1; off < 64; off <<= 1) {
    int y = __shfl_up(x, off, 64);
    if (lane >= off) x += y;
  }
  if (lane == 63) ws[wv] = x;
  __syncthreads();
  int wbase = 0;
  for (int w = 0; w < wv; ++w) wbase += ws[w];
  int incl = x + wbase;
  if (tid == 0) {
    int tot = ws[0] + ws[1] + ws[2] + ws[3];
    s_total = tot;
    unsigned long long st = (b == 0) ? (2ULL << 62) : (1ULL << 62);
    atomicExch(&desc[b], st | (unsigned long long)(unsigned int)tot);
    if (b == 0) s_prev = 0u;
  }
  __syncthreads();
  if (b > 0 && wv == 0) {
    unsigned int running = 0;
    int j = b - 1;
    while (true) {
      int idx = j - lane;
      unsigned long long d;
      if (idx >= 0) {
        do { d = atomicAdd(&desc[idx], 0ULL); } while ((d >> 62) == 0ULL);
      } else {
        d = (2ULL << 62);
      }
      unsigned long long ball = __ballot((d >> 62) == 2ULL);
      int fp = ball ? (__ffsll((unsigned long long)ball) - 1) : 64;
      unsigned int contrib = (lane <= fp) ? (unsigned int)(d & 0xffffffffULL) : 0u;
      #pragma unroll
      for (int o = 32; o; o >>= 1) contrib += __shfl_xor(contrib, o, 64);
      running += contrib;
      if (fp < 64) break;
      j -= 64;
    }
    if (lane == 0) {
      atomicExch(&desc[b], (2ULL << 62) |
                 (unsigned long long)(unsigned int)(running + (unsigned int)s_total));
      s_prev = running;
    }
  }
  __syncthreads();
  int tot = (int)s_prev + incl;
  if (i < n) {
    row_ptr[i + 1] = tot;
    dinv[i] = rsqrtf((float)v + 1.0f);
  }
  if (i == 0) row_ptr[0] = 0;
}

// Pure atomic-free CSR fill: pos = row_ptr[dst] + rank[e].
__global__ __launch_bounds__(256) void fill_kernel(
    const int* __restrict__ eraw, const unsigned int* __restrict__ xraw,
    const int* __restrict__ row_ptr, const int* __restrict__ rank,
    const float* __restrict__ dinv, uint2* __restrict__ csr, int E) {
  int f32, i64;
  block_detect(xraw, (const unsigned int*)eraw, &f32, &i64);
  int e = blockIdx.x * 256 + threadIdx.x;
  if (e >= E) return;
  int s, d;
  if (i64) { s = eraw[2 * e]; d = eraw[2 * (E + e)]; }
  else     { s = eraw[e];     d = eraw[E + e]; }
  int pos = row_ptr[d] + rank[e];
  uint2 v;
  v.x = (unsigned int)s;
  v.y = __float_as_uint(dinv[s] * dinv[d]);
  csr[pos] = v;
}

// ---- generic per-lane vector of DW dwords ----
template<int DW> struct UVec { unsigned int d[DW]; };
template<int DW>
__device__ __forceinline__ UVec<DW> uload(const unsigned int* p) {
  UVec<DW> r;
  if constexpr (DW == 4) { uint4 v = *(const uint4*)p; r.d[0]=v.x; r.d[1]=v.y; r.d[2]=v.z; r.d[3]=v.w; }
  else if constexpr (DW == 2) { uint2 v = *(const uint2*)p; r.d[0]=v.x; r.d[1]=v.y; }
  else { r.d[0] = *p; }
  return r;
}
template<int DW>
__device__ __forceinline__ void ustore(unsigned int* p, const UVec<DW>& v) {
  if constexpr (DW == 4) { *(uint4*)p = make_uint4(v.d[0], v.d[1], v.d[2], v.d[3]); }
  else if constexpr (DW == 2) { *(uint2*)p = make_uint2(v.d[0], v.d[1]); }
  else { *p = v.d[0]; }
}

// Fused agg(FIN, bias, relu) -> LDS tile -> MFMA @ Wf(FIN x FOUT) -> Hout.
template<int FIN, int FOUT, int LPG>
__global__ __launch_bounds__(256) void aggemm_kernel(
    const unsigned short* __restrict__ Hin,
    const int* __restrict__ row_ptr, const uint2* __restrict__ csr,
    const float* __restrict__ dinv, const unsigned short* __restrict__ bias,
    const unsigned short* __restrict__ Wf, unsigned short* __restrict__ Hout, int n) {
  constexpr int DW  = FIN / LPG / 2;     // dwords per lane
  constexpr int NPB = 256 / LPG;         // nodes per block (16 or 32)
  constexpr int LD  = FIN + 8;           // LDS row pitch in shorts
  constexpr int KB  = FIN / 32;
  constexpr int CT  = FOUT / 16;
  constexpr int MT  = NPB / 16;
  __shared__ unsigned short T[NPB * LD];
  const int r = threadIdx.x / LPG, l = threadIdx.x % LPG;
  const int node0 = blockIdx.x * NPB;
  const int g = node0 + r;
  const unsigned int* H2 = (const unsigned int*)Hin;
  UVec<DW> o;
  #pragma unroll
  for (int d = 0; d < DW; ++d) o.d[d] = 0u;
  if (g < n) {
    float di = dinv[g];
    float c0 = di * di;
    float a[2 * DW];
    UVec<DW> hv = uload<DW>(H2 + (size_t)g * (FIN / 2) + l * DW);
    #pragma unroll
    for (int d = 0; d < DW; ++d) {
      a[2*d]   = b2f(hv.d[d] & 0xffffu) * c0;
      a[2*d+1] = b2f(hv.d[d] >> 16) * c0;
    }
    const int e0 = row_ptr[g], e1 = row_ptr[g + 1];
    for (int base = e0; base < e1; base += LPG) {
      int cnt = e1 - base < LPG ? e1 - base : LPG;
      uint2 my = csr[(base + l < e1) ? (base + l) : (e1 - 1)];
      for (int j = 0; j < cnt; ++j) {
        int s = __shfl((int)my.x, j, LPG);
        float c = __uint_as_float(__shfl((int)my.y, j, LPG));
        UVec<DW> v = uload<DW>(H2 + (size_t)s * (FIN / 2) + l * DW);
        #pragma unroll
        for (int d = 0; d < DW; ++d) {
          a[2*d]   = fmaf(b2f(v.d[d] & 0xffffu), c, a[2*d]);
          a[2*d+1] = fmaf(b2f(v.d[d] >> 16), c, a[2*d+1]);
        }
      }
    }
    UVec<DW> bb = uload<DW>((const unsigned int*)bias + l * DW);
    #pragma unroll
    for (int d = 0; d < DW; ++d) {
      float lo = fmaxf(a[2*d]   + b2f(bb.d[d] & 0xffffu), 0.f);
      float hi = fmaxf(a[2*d+1] + b2f(bb.d[d] >> 16), 0.f);
      o.d[d] = (unsigned int)f2b(lo) | ((unsigned int)f2b(hi) << 16);
    }
  }
  ustore<DW>((unsigned int*)&T[r * LD + l * DW * 2], o);
  __syncthreads();
  // ---- MFMA phase: wave w covers (mt, ct) combo ----
  const int w = threadIdx.x >> 6;
  if (w < MT * CT && node0 < n) {
    const int mt = w / CT, ct = w % CT;
    const int ll = threadIdx.x & 63;
    const int r16 = ll & 15, quad = ll >> 4;
    bf8_t afrag[KB], bfrag[KB];
    #pragma unroll
    for (int kb = 0; kb < KB; ++kb) {
      afrag[kb] = *(const bf8_t*)(&T[(mt * 16 + r16) * LD + quad * 8 + kb * 32]);
      bfrag[kb] = *(const bf8_t*)(Wf + ((ct * KB + kb) * 64 + ll) * 8);
    }
    f4_t acc = {0.f, 0.f, 0.f, 0.f};
    #pragma unroll
    for (int kb = 0; kb < KB; ++kb)
      acc = __builtin_amdgcn_mfma_f32_16x16x32_bf16(afrag[kb], bfrag[kb], acc, 0, 0, 0);
    #pragma unroll
    for (int rr = 0; rr < 4; ++rr) {
      int node = node0 + mt * 16 + quad * 4 + rr;
      if (node < n)
        Hout[(size_t)node * FOUT + ct * 16 + r16] = f2b(acc[rr]);
    }
  }
}

// Fused last-layer agg + mean-pool. LPG=8, 32 nodes/block.
__global__ __launch_bounds__(256) void agg_pool_kernel(
    const unsigned short* __restrict__ Hin,
    const int* __restrict__ row_ptr, const uint2* __restrict__ csr,
    const float* __restrict__ dinv, const unsigned short* __restrict__ bias,
    const int* __restrict__ batch, float* __restrict__ pooled,
    float* __restrict__ cnt, int n) {
  __shared__ float acc[N_GRAPHS * 16];
  __shared__ float ccnt[N_GRAPHS];
  for (int i = threadIdx.x; i < N_GRAPHS * 16; i += 256) acc[i] = 0.f;
  if (threadIdx.x < N_GRAPHS) ccnt[threadIdx.x] = 0.f;
  __syncthreads();
  const int r = threadIdx.x >> 3, l = threadIdx.x & 7;
  const int g = blockIdx.x * 32 + r;
  if (g < n) {
    const unsigned int* H2 = (const unsigned int*)Hin;
    float di = dinv[g];
    float c0 = di * di;
    unsigned int hv = H2[(size_t)g * 8 + l];
    float a0 = b2f(hv & 0xffffu) * c0;
    float a1 = b2f(hv >> 16) * c0;
    const int e0 = row_ptr[g], e1 = row_ptr[g + 1];
    for (int base = e0; base < e1; base += 8) {
      int cnt2 = e1 - base < 8 ? e1 - base : 8;
      uint2 my = csr[(base + l < e1) ? (base + l) : (e1 - 1)];
      for (int j = 0; j < cnt2; ++j) {
        int s = __shfl((int)my.x, j, 8);
        float c = __uint_as_float(__shfl((int)my.y, j, 8));
        unsigned int v = H2[(size_t)s * 8 + l];
        a0 = fmaf(b2f(v & 0xffffu), c, a0);
        a1 = fmaf(b2f(v >> 16), c, a1);
      }
    }
    unsigned int bb = ((const unsigned int*)bias)[l];
    a0 = fmaxf(a0 + b2f(bb & 0xffffu), 0.f);
    a1 = fmaxf(a1 + b2f(bb >> 16), 0.f);
    int gb = batch[g];
    atomicAdd(&acc[gb * 16 + l * 2 + 0], a0);
    atomicAdd(&acc[gb * 16 + l * 2 + 1], a1);
    if (l == 0) atomicAdd(&ccnt[gb], 1.f);
  }
  __syncthreads();
  for (int i = threadIdx.x; i < N_GRAPHS * 16; i += 256)
    if (acc[i] != 0.f) atomicAdd(&pooled[i], acc[i]);
  if (threadIdx.x < N_GRAPHS && ccnt[threadIdx.x] != 0.f)
    atomicAdd(&cnt[threadIdx.x], ccnt[threadIdx.x]);
}

__global__ __launch_bounds__(256) void final_kernel(const float* __restrict__ pooled,
    const float* __restrict__ cnt, const unsigned short* __restrict__ wc,
    void* __restrict__ out, const unsigned int* __restrict__ xraw) {
  int f32;
  block_detect(xraw, nullptr, &f32, nullptr);
  int id = blockIdx.x * 256 + threadIdx.x;
  if (id >= N_GRAPHS * N_CLASSES) return;
  const unsigned short* Wlin = wc + WOFF[8];
  const unsigned short* blin = wc + WOFF[9];
  int g = id / N_CLASSES, c = id - g * N_CLASSES;
  float inv = 1.0f / fmaxf(cnt[g], 1.0f);
  float a = b2f(blin[c]);
  #pragma unroll
  for (int f = 0; f < 16; ++f)
    a = fmaf(pooled[g * 16 + f] * inv, b2f(Wlin[f * N_CLASSES + c]), a);
  if (f32) ((float*)out)[id] = a;
  else     ((unsigned short*)out)[id] = f2b(a);
}

extern "C" void kernel_launch(void* const* d_in, const int* in_sizes, int n_in,
                              void* d_out, int out_size, void* d_ws, size_t ws_size,
                              hipStream_t stream) {
  const unsigned int* xraw = (const unsigned int*)d_in[0];
  const int* eraw          = (const int*)d_in[1];
  const int* braw          = (const int*)d_in[2];

  const int N = in_sizes[2];
  const int E = in_sizes[1] / 2;
  const int nb = (N + 255) / 256;

  char* p = (char*)d_ws;
  auto alloc = [&](size_t bytes) -> void* {
    void* r = (void*)p;
    p += (bytes + 255) & ~(size_t)255;
    return r;
  };
  // zero region: deg(padded, 64B/counter) | desc | pooled | cnt  (one memset)
  const size_t off_desc = ((size_t)N * 64 + 255) & ~(size_t)255;
  const size_t off_pool = (off_desc + (size_t)nb * 8 + 255) & ~(size_t)255;
  const size_t ztotal   = off_pool + (N_GRAPHS * 16 + N_GRAPHS) * 4;
  char* zbase = (char*)alloc(ztotal);
  int*   deg    = (int*)zbase;
  unsigned long long* desc = (unsigned long long*)(zbase + off_desc);
  float* pooled = (float*)(zbase + off_pool);
  float* cntf   = pooled + N_GRAPHS * 16;

  int*   row_ptr  = (int*)  alloc((size_t)(N + 1) * 4);
  int*   rank     = (int*)  alloc((size_t)E * 4);
  float* dinv     = (float*)alloc((size_t)N * 4);
  int*   batch32  = (int*)  alloc((size_t)N * 4);
  uint2* csr      = (uint2*)alloc((size_t)E * 8);
  unsigned short* wcan  = (unsigned short*)alloc((size_t)WTOTAL * 2);
  unsigned short* hbufA = (unsigned short*)alloc((size_t)N * 128 * 2);
  unsigned short* hbufB = (unsigned short*)alloc((size_t)N * 128 * 2);

  hipMemsetAsync(zbase, 0, ztotal, stream);

  WPtrs wp;
  for (int i = 0; i < 10; ++i) wp.p[i] = d_in[3 + i];

  const int BW = (WTOTAL + 255) / 256;
  const int BB = nb;
  const int BE = (E + 255) / 256;
  const int G1 = (N + 127) / 128;
  cvtwe_gemm1_kernel<<<G1 + BW + BB + BE, 256, 0, stream>>>(xraw, wp, wcan,
      braw, batch32, eraw, deg, rank, hbufA, G1, BW, BB, N, E);

  scan_kernel<<<nb, 256, 0, stream>>>(deg, row_ptr, dinv, desc, N);

  const unsigned short* b1 = wcan + WOFF[1];
  const unsigned short* W2 = wcan + WOFF[2];
  const unsigned short* b2 = wcan + WOFF[3];
  const unsigned short* W3 = wcan + WOFF[4];
  const unsigned short* b3 = wcan + WOFF[5];
  const unsigned short* W4 = wcan + WOFF[6];
  const unsigned short* b4 = wcan + WOFF[7];

  fill_kernel<<<BE, 256, 0, stream>>>(eraw, xraw, row_ptr, rank, dinv, csr, E);

  aggemm_kernel<128, 64, 16><<<(N + 15) / 16, 256, 0, stream>>>(
      hbufA, row_ptr, csr, dinv, b1, W2, hbufB, N);
  aggemm_kernel<64, 32, 8><<<(N + 31) / 32, 256, 0, stream>>>(
      hbufB, row_ptr, csr, dinv, b2, W3, hbufA, N);
  aggemm_kernel<32, 16, 8><<<(N + 31) / 32, 256, 0, stream>>>(
      hbufA, row_ptr, csr, dinv, b3, W4, hbufB, N);
  agg_pool_kernel<<<(N + 31) / 32, 256, 0, stream>>>(hbufB, row_ptr, csr, dinv, b4,
      batch32, pooled, cntf, N);

  final_kernel<<<(N_GRAPHS * N_CLASSES + 255) / 256, 256, 0, stream>>>(pooled, cntf, wcan, d_out, xraw);
}